// Round 6
// baseline (161.519 us; speedup 1.0000x reference)
//
#include <hip/hip_runtime.h>
#include <hip/hip_bf16.h>

// N=2, L=8192, dim=256, H=8, Pd=32. seg = n*8+h (16 segs of 8192 rows).
// K1 k_prepw: Wq/Wv/Wk fp32 -> bf16 MFMA-fragment order (tiny).
// K2 k_gemm : register-resident fused GEMM. grid 1024 = 512 row-blocks
//             (32 rows) x 2 col-halves (128 cols). block 256, 4 waves;
//             wave = 1 head (32 cols, 2 j-tiles). Three sequential passes
//             (q -> v -> k) keep live VGPRs low -> __launch_bounds__(256,4)
//             = 16 waves/CU for latency hiding. No k-loop barriers.
//             c/cden via shuffles; 32-row tile totals; pk stored bf16.
// K3 k_scan : per-block prefix over `tot`; each 32-lane group owns 32 rows,
//             each lane carries BOTH running num and den (no shuffle/LDS op
//             in the serial chain); division off the carried chain.
// ws floats: Wf[bf16 196608] = 98304 | pk[bf16 4194304] = 2097152 |
//            c 131072 | cd 131072 | tot 16*256*64 = 262144   (~10.4 MB)

typedef __attribute__((ext_vector_type(8))) short short8;  // 8 bf16
typedef __attribute__((ext_vector_type(4))) float f32x4;

__device__ __forceinline__ float phi_f(float x) {
    return x > 0.f ? x + 1.f : __expf(x);   // elu(x)+1
}
__device__ __forceinline__ unsigned short f2bf(float x) {
    __hip_bfloat16 h = __float2bfloat16(x);   // RNE
    return *reinterpret_cast<unsigned short*>(&h);
}
__device__ __forceinline__ float bf2f(unsigned short u) {
    return __uint_as_float(((unsigned int)u) << 16);
}
__device__ __forceinline__ short8 cvt8(float4 f0, float4 f1) {
    short8 o;
    o[0] = f2bf(f0.x); o[1] = f2bf(f0.y); o[2] = f2bf(f0.z); o[3] = f2bf(f0.w);
    o[4] = f2bf(f1.x); o[5] = f2bf(f1.y); o[6] = f2bf(f1.z); o[7] = f2bf(f1.w);
    return o;
}

// ---------------- K1: W -> bf16 fragment order ----------------------------
// chunk cc (per mat): ln=cc&15, qd=(cc>>4)&3, kt=(cc>>6)&7, jt=cc>>9.
__global__ __launch_bounds__(256) void k_prepw(
        const float* __restrict__ Wq, const float* __restrict__ Wk,
        const float* __restrict__ Wv, unsigned short* __restrict__ Wf)
{
    const int g = blockIdx.x * 256 + threadIdx.x;   // 0..24575
    const int mat = g >> 13, cc = g & 8191;         // 0=q, 1=v, 2=k
    const float* src = (mat == 0) ? Wq : (mat == 1 ? Wv : Wk);
    const int ln = cc & 15, qd = (cc >> 4) & 3, kt = (cc >> 6) & 7, jt = cc >> 9;
    const float* s = src + (size_t)(jt * 16 + ln) * 256 + kt * 32 + qd * 8;
    *(short8*)(Wf + (size_t)g * 8) = cvt8(*(const float4*)s, *(const float4*)(s + 4));
}

// ---------------- K2: register-resident fused GEMM ------------------------
__global__ __launch_bounds__(256, 4) void k_gemm(
        const float* __restrict__ Y, const float* __restrict__ X,
        const unsigned short* __restrict__ Wf,
        unsigned short* __restrict__ pk_out,
        float* __restrict__ c_out, float* __restrict__ cd_out,
        float* __restrict__ tot)
{
    __shared__ float scc[32][4], scd[32][4];
    __shared__ __align__(16) unsigned short spk[32 * 136];   // 8.5 KB

    const int bx = blockIdx.x;
    const int rb = bx >> 1;               // rows 32rb..32rb+31
    const int chalf = bx & 1;             // cols chalf*128..+127 (heads 4c..4c+3)
    const int n = rb >> 8;
    const int tile = rb & 255;
    const int lseg0 = tile * 32;
    const bool hasprev = (tile != 0);
    const int t = threadIdx.x, w = t >> 6, lane = t & 63;
    const int head = chalf * 4 + w;
    const int ln = lane & 15, qd = lane >> 4;
    const int fl = qd * 16 + ln;

    const short8* W8 = (const short8*)Wf;
    const int rt0 = rb * 2;
    const int rtp = hasprev ? rt0 - 1 : 0;

    const float* Yp = Y + (size_t)(rtp * 16 + ln) * 256 + qd * 8;
    const float* Y0 = Y + (size_t)(rt0 * 16 + ln) * 256 + qd * 8;
    const float* Y1 = Y0 + 16 * 256;
    const float* X0 = X + (size_t)(rt0 * 16 + ln) * 256 + qd * 8;
    const float* X1 = X0 + 16 * 256;

    // ---- q pass ----
    f32x4 aq[2][2], aqp[2];
#pragma unroll
    for (int j = 0; j < 2; ++j) {
        aq[0][j] = (f32x4){0.f, 0.f, 0.f, 0.f};
        aq[1][j] = (f32x4){0.f, 0.f, 0.f, 0.f};
        aqp[j]   = (f32x4){0.f, 0.f, 0.f, 0.f};
    }
#pragma unroll
    for (int kt = 0; kt < 8; ++kt) {
        const int ko = kt * 32;
        short8 ayp = cvt8(*(const float4*)(Yp + ko), *(const float4*)(Yp + ko + 4));
        short8 ay0 = cvt8(*(const float4*)(Y0 + ko), *(const float4*)(Y0 + ko + 4));
        short8 ay1 = cvt8(*(const float4*)(Y1 + ko), *(const float4*)(Y1 + ko + 4));
#pragma unroll
        for (int j = 0; j < 2; ++j) {
            short8 b = W8[(size_t)(((0 * 16 + head * 2 + j) * 8 + kt) * 4) * 16 + fl];
            aqp[j]   = __builtin_amdgcn_mfma_f32_16x16x32_bf16(ayp, b, aqp[j], 0, 0, 0);
            aq[0][j] = __builtin_amdgcn_mfma_f32_16x16x32_bf16(ay0, b, aq[0][j], 0, 0, 0);
            aq[1][j] = __builtin_amdgcn_mfma_f32_16x16x32_bf16(ay1, b, aq[1][j], 0, 0, 0);
        }
    }
#pragma unroll
    for (int i = 0; i < 2; ++i)
#pragma unroll
        for (int j = 0; j < 2; ++j)
#pragma unroll
            for (int r = 0; r < 4; ++r) aq[i][j][r] = phi_f(aq[i][j][r]);
    float pprev[2];
#pragma unroll
    for (int j = 0; j < 2; ++j) {
        float p15 = __shfl(aqp[j][3], 48 + ln);   // last row of prev 32-tile
        pprev[j] = hasprev ? phi_f(p15) : 0.f;
    }

    // ---- v pass ----
    f32x4 av[2][2];
#pragma unroll
    for (int j = 0; j < 2; ++j) {
        av[0][j] = (f32x4){0.f, 0.f, 0.f, 0.f};
        av[1][j] = (f32x4){0.f, 0.f, 0.f, 0.f};
    }
#pragma unroll
    for (int kt = 0; kt < 8; ++kt) {
        const int ko = kt * 32;
        short8 ax0 = cvt8(*(const float4*)(X0 + ko), *(const float4*)(X0 + ko + 4));
        short8 ax1 = cvt8(*(const float4*)(X1 + ko), *(const float4*)(X1 + ko + 4));
#pragma unroll
        for (int j = 0; j < 2; ++j) {
            short8 b = W8[(size_t)(((1 * 16 + head * 2 + j) * 8 + kt) * 4) * 16 + fl];
            av[0][j] = __builtin_amdgcn_mfma_f32_16x16x32_bf16(ax0, b, av[0][j], 0, 0, 0);
            av[1][j] = __builtin_amdgcn_mfma_f32_16x16x32_bf16(ax1, b, av[1][j], 0, 0, 0);
        }
    }

    // ---- c, cden (consumes aq, av) ----
    float cc_[2][4], cd_[2][4];
#pragma unroll
    for (int i = 0; i < 2; ++i)
#pragma unroll
        for (int r = 0; r < 4; ++r) { cc_[i][r] = 0.f; cd_[i][r] = 0.f; }
#pragma unroll
    for (int j = 0; j < 2; ++j) {
        float carry = pprev[j];
#pragma unroll
        for (int i = 0; i < 2; ++i) {
            const float p0 = aq[i][j][0], p1 = aq[i][j][1], p2 = aq[i][j][2], p3 = aq[i][j][3];
            const float up3 = __shfl_up(p3, 16);
            const float prev0 = (qd == 0) ? carry : up3;
            const float d0 = p0 - prev0, d1 = p1 - p0, d2 = p2 - p1, d3 = p3 - p2;
            cc_[i][0] += d0 * av[i][j][0]; cd_[i][0] += d0;
            cc_[i][1] += d1 * av[i][j][1]; cd_[i][1] += d1;
            cc_[i][2] += d2 * av[i][j][2]; cd_[i][2] += d2;
            cc_[i][3] += d3 * av[i][j][3]; cd_[i][3] += d3;
            carry = __shfl(p3, ln + 48);
        }
    }
#pragma unroll
    for (int i = 0; i < 2; ++i)
#pragma unroll
        for (int r = 0; r < 4; ++r) {
            float x = cc_[i][r];
            x += __shfl_xor(x, 1); x += __shfl_xor(x, 2);
            x += __shfl_xor(x, 4); x += __shfl_xor(x, 8);
            float y = cd_[i][r];
            y += __shfl_xor(y, 1); y += __shfl_xor(y, 2);
            y += __shfl_xor(y, 4); y += __shfl_xor(y, 8);
            if (ln == 0) {
                scc[i * 16 + qd * 4 + r][w] = x;
                scd[i * 16 + qd * 4 + r][w] = y;
            }
        }
    __syncthreads();
    if (t < 128) {
        const int row = t & 31, hl = t >> 5;
        const size_t gi = (size_t)(n * 8 + chalf * 4 + hl) * 8192 + lseg0 + row;
        c_out[gi]  = scc[row][hl];
        cd_out[gi] = scd[row][hl];
    }

    // ---- k pass (reloads X; consumes nothing else) ----
    f32x4 ak[2][2];
#pragma unroll
    for (int j = 0; j < 2; ++j) {
        ak[0][j] = (f32x4){0.f, 0.f, 0.f, 0.f};
        ak[1][j] = (f32x4){0.f, 0.f, 0.f, 0.f};
    }
#pragma unroll
    for (int kt = 0; kt < 8; ++kt) {
        const int ko = kt * 32;
        short8 ax0 = cvt8(*(const float4*)(X0 + ko), *(const float4*)(X0 + ko + 4));
        short8 ax1 = cvt8(*(const float4*)(X1 + ko), *(const float4*)(X1 + ko + 4));
#pragma unroll
        for (int j = 0; j < 2; ++j) {
            short8 b = W8[(size_t)(((2 * 16 + head * 2 + j) * 8 + kt) * 4) * 16 + fl];
            ak[0][j] = __builtin_amdgcn_mfma_f32_16x16x32_bf16(ax0, b, ak[0][j], 0, 0, 0);
            ak[1][j] = __builtin_amdgcn_mfma_f32_16x16x32_bf16(ax1, b, ak[1][j], 0, 0, 0);
        }
    }
#pragma unroll
    for (int i = 0; i < 2; ++i)
#pragma unroll
        for (int j = 0; j < 2; ++j)
#pragma unroll
            for (int r = 0; r < 4; ++r) ak[i][j][r] = phi_f(ak[i][j][r]);

    // ---- 32-row tile totals ----
#pragma unroll
    for (int j = 0; j < 2; ++j) {
        float tn = 0.f, td = 0.f;
#pragma unroll
        for (int i = 0; i < 2; ++i)
#pragma unroll
            for (int r = 0; r < 4; ++r) {
                const int row = i * 16 + qd * 4 + r;
                const float pv = ak[i][j][r];
                tn += scc[row][w] * pv;
                td += scd[row][w] * pv;
            }
        tn += __shfl_xor(tn, 16); tn += __shfl_xor(tn, 32);
        td += __shfl_xor(td, 16); td += __shfl_xor(td, 32);
        if (qd == 0) {
            const int d = (j & 1) * 16 + ln;
            const size_t bi = ((size_t)(n * 8 + head) * 256 + tile) * 64;
            tot[bi + d]      = tn;
            tot[bi + 32 + d] = td;
        }
    }

    // ---- pk -> global bf16 via LDS transpose (32 rows x 128 cols) ----
#pragma unroll
    for (int i = 0; i < 2; ++i)
#pragma unroll
        for (int j = 0; j < 2; ++j)
#pragma unroll
            for (int r = 0; r < 4; ++r)
                spk[(i * 16 + qd * 4 + r) * 136 + w * 32 + j * 16 + ln] = f2bf(ak[i][j][r]);
    __syncthreads();
#pragma unroll
    for (int it = 0; it < 2; ++it) {
        const int idx = t + 256 * it;     // 512 chunks (32 rows x 16 col-groups)
        const int row = idx >> 4, cg = idx & 15;
        short8 vals = *(const short8*)&spk[row * 136 + cg * 8];
        const int hl = cg >> 2, d8 = (cg & 3) * 8;
        *(short8*)(pk_out + ((size_t)(n * 8 + chalf * 4 + hl) * 8192 + lseg0 + row) * 32 + d8) = vals;
    }
}

// ---------------- K3: prefix + scan + divide + store ----------------------
// grid 512 = 16 segs x 32 blocks (256 rows). 8 groups of 32 lanes; group g
// owns rows g*32..+31; lane d carries BOTH running num and den.
__global__ __launch_bounds__(256) void k_scan(
        const unsigned short* __restrict__ pk, const float* __restrict__ c,
        const float* __restrict__ cd, const float* __restrict__ tot,
        float* __restrict__ out)
{
    __shared__ __align__(16) unsigned short spk[256 * 32];  // 16 KB bf16
    __shared__ float sc[256], sd[256];
    __shared__ float wsum[4][64];
    __shared__ float stile[8][64];

    const int bx = blockIdx.x, seg = bx >> 5, blk = bx & 31;
    const int n = seg >> 3, h = seg & 7;
    const int t = threadIdx.x, l0 = blk * 256;
    const int wv = t >> 6, lane = t & 63;

    // prefix over tiles before this block (4-way wave split)
    float pre = 0.f;
    const int T = blk * 8;
    for (int i = wv; i < T; i += 4)
        pre += tot[((size_t)seg * 256 + i) * 64 + lane];
    wsum[wv][lane] = pre;

    // own-block tile totals
#pragma unroll
    for (int i = 0; i < 2; ++i) {
        const int idx = t + 256 * i;      // 512 entries
        stile[idx >> 6][idx & 63] = tot[((size_t)seg * 256 + T + (idx >> 6)) * 64 + (idx & 63)];
    }
#pragma unroll
    for (int i = 0; i < 4; ++i) {
        const int idx = t + 256 * i;      // 1024 short8 chunks
        *(short8*)&spk[idx * 8] = *(const short8*)(pk + ((size_t)seg * 8192 + l0) * 32 + idx * 8);
    }
    sc[t] = c[(size_t)seg * 8192 + l0 + t];
    sd[t] = cd[(size_t)seg * 8192 + l0 + t];
    __syncthreads();

    const int g = t >> 5, d = t & 31;     // group g: rows g*32..+31
    const int m0 = g * 32;
    float rn = wsum[0][d] + wsum[1][d] + wsum[2][d] + wsum[3][d];
    float rd_ = wsum[0][32 + d] + wsum[1][32 + d] + wsum[2][32 + d] + wsum[3][32 + d];
    for (int i = 0; i < g; ++i) { rn += stile[i][d]; rd_ += stile[i][32 + d]; }

    float* ob = out + ((size_t)n * 8192 + l0 + m0) * 256 + h * 32 + d;
#pragma unroll
    for (int p = 0; p < 32; ++p) {
        const int m = m0 + p;
        const float pkv = bf2f(spk[m * 32 + d]);
        rn  += sc[m] * pkv;
        rd_ += sd[m] * pkv;
        ob[(size_t)p * 256] = rn / rd_;   // div off the carried chain
    }
}

extern "C" void kernel_launch(void* const* d_in, const int* in_sizes, int n_in,
                              void* d_out, int out_size, void* d_ws, size_t ws_size,
                              hipStream_t stream)
{
    const float* Y  = (const float*)d_in[0];
    const float* X  = (const float*)d_in[1];
    const float* Wq = (const float*)d_in[2];
    const float* Wk = (const float*)d_in[3];
    const float* Wv = (const float*)d_in[4];
    float* out = (float*)d_out;

    float* ws = (float*)d_ws;
    unsigned short* Wf = (unsigned short*)ws;                 // 196608 bf16
    unsigned short* pk = (unsigned short*)(ws + 98304);       // 4194304 bf16
    float* c   = ws + 98304 + 2097152;
    float* cd  = c  + 131072;
    float* tot = cd + 131072;    // 16*256*64

    hipLaunchKernelGGL(k_prepw, dim3(96),   dim3(256), 0, stream, Wq, Wk, Wv, Wf);
    hipLaunchKernelGGL(k_gemm,  dim3(1024), dim3(256), 0, stream,
                       Y, X, Wf, pk, c, cd, tot);
    hipLaunchKernelGGL(k_scan,  dim3(512),  dim3(256), 0, stream, pk, c, cd, tot, out);
}

// Round 7
// 112.025 us; speedup vs baseline: 1.4418x; 1.4418x over previous
//
#include <hip/hip_runtime.h>
#include <hip/hip_bf16.h>

// N=2, L=8192, dim=256, H=8, Pd=32. seg = n*8+h (16 segs of 8192 rows).
// K1 k_prepw: Wq/Wv/Wk fp32 -> bf16 MFMA-fragment order (tiny).
// K2 k_gemm : 32 rows/block, grid 512, block 512 (8 waves; wave = head).
//             Full-K LDS staging of Y/X tiles (coalesced 1KB/instr loads,
//             stride-280 bf16 padding), ONE barrier, no k-loop barriers.
//             B-fragments stream from L2 (Wf fragment order). Boundary
//             pq[mbase-1] via one extra staged row + masked A-frag MFMA.
//             c/cden via shuffles; 32-row tile totals; pk stored bf16.
// K3 k_scan : 128 rows/block, grid 1024. Deep-ILP prefix over `tot`
//             (8 independent accumulators), serial 32-step dual-carry walk
//             (num+den in-lane), division off the carried chain.
// ws floats: Wf[bf16 196608]=98304 | pk[bf16 4194304]=2097152 |
//            c 131072 | cd 131072 | tot 16*256*64 = 262144   (~10.4 MB)

typedef __attribute__((ext_vector_type(8))) short short8;  // 8 bf16
typedef __attribute__((ext_vector_type(4))) float f32x4;

__device__ __forceinline__ float phi_f(float x) {
    return x > 0.f ? x + 1.f : __expf(x);   // elu(x)+1
}
__device__ __forceinline__ unsigned short f2bf(float x) {
    __hip_bfloat16 h = __float2bfloat16(x);   // RNE
    return *reinterpret_cast<unsigned short*>(&h);
}
__device__ __forceinline__ float bf2f(unsigned short u) {
    return __uint_as_float(((unsigned int)u) << 16);
}

// ---------------- K1: W -> bf16 fragment order ----------------------------
// chunk cc (per mat): ln=cc&15, qd=(cc>>4)&3, kt=(cc>>6)&7, jt=cc>>9.
__global__ __launch_bounds__(256) void k_prepw(
        const float* __restrict__ Wq, const float* __restrict__ Wk,
        const float* __restrict__ Wv, unsigned short* __restrict__ Wf)
{
    const int g = blockIdx.x * 256 + threadIdx.x;   // 0..24575
    const int mat = g >> 13, cc = g & 8191;         // 0=q, 1=v, 2=k
    const float* src = (mat == 0) ? Wq : (mat == 1 ? Wv : Wk);
    const int ln = cc & 15, qd = (cc >> 4) & 3, kt = (cc >> 6) & 7, jt = cc >> 9;
    const float* s = src + (size_t)(jt * 16 + ln) * 256 + kt * 32 + qd * 8;
    float4 f0 = *(const float4*)s, f1 = *(const float4*)(s + 4);
    short8 o;
    o[0] = f2bf(f0.x); o[1] = f2bf(f0.y); o[2] = f2bf(f0.z); o[3] = f2bf(f0.w);
    o[4] = f2bf(f1.x); o[5] = f2bf(f1.y); o[6] = f2bf(f1.z); o[7] = f2bf(f1.w);
    *(short8*)(Wf + (size_t)g * 8) = o;
}

// ---------------- K2: LDS-staged fused GEMM -------------------------------
#define LDA 280   // shorts/row: 140 dwords == 12 mod 32 -> 2-way max (free)

__global__ __launch_bounds__(512, 4) void k_gemm(
        const float* __restrict__ Y, const float* __restrict__ X,
        const unsigned short* __restrict__ Wf,
        unsigned short* __restrict__ pk_out,
        float* __restrict__ c_out, float* __restrict__ cd_out,
        float* __restrict__ tot)
{
    __shared__ __align__(16) unsigned short Ys[33 * LDA];   // 18.0 KB (+1 boundary row)
    __shared__ __align__(16) unsigned short Xs[32 * LDA];   // 17.5 KB
    __shared__ float scc[32][8], scd[32][8];                //  2.0 KB
    __shared__ __align__(16) unsigned short spk[32 * 264];  // 16.5 KB

    const int rb = blockIdx.x;            // rows 32rb..32rb+31
    const int n = rb >> 8, tile = rb & 255;
    const int mbase = rb * 32, lseg0 = tile * 32;
    const bool hasprev = (tile != 0);
    const int t = threadIdx.x, w = t >> 6, lane = t & 63;   // wave w = head w
    const int ln = lane & 15, qd = lane >> 4;

    // ---- staging: Y+X tiles, fully coalesced (1KB per wave-instr) ----
#pragma unroll
    for (int it = 0; it < 8; ++it) {
        const int idx = t + it * 512;                 // 0..4095
        const int half = idx >> 11, row = (idx >> 6) & 31, c4 = idx & 63;
        const float* s = (half ? X : Y) + (size_t)(mbase + row) * 256 + c4 * 4;
        float4 f = *(const float4*)s;
        ushort4 h4;
        h4.x = f2bf(f.x); h4.y = f2bf(f.y); h4.z = f2bf(f.z); h4.w = f2bf(f.w);
        unsigned short* dst = half ? Xs : Ys;
        *(ushort4*)&dst[row * LDA + c4 * 4] = h4;
    }
    if (t < 64) {                                     // boundary row mbase-1
        const int prow = hasprev ? mbase - 1 : mbase; // clamped; masked later
        float4 f = *(const float4*)(Y + (size_t)prow * 256 + t * 4);
        ushort4 h4;
        h4.x = f2bf(f.x); h4.y = f2bf(f.y); h4.z = f2bf(f.z); h4.w = f2bf(f.w);
        *(ushort4*)&Ys[32 * LDA + t * 4] = h4;
    }
    __syncthreads();

    // ---- single k-loop: q, v, k + boundary tile, no barriers ----
    f32x4 aq[2][2], av[2][2], akk[2][2], aqp[2];
#pragma unroll
    for (int i = 0; i < 2; ++i)
#pragma unroll
        for (int j = 0; j < 2; ++j) {
            aq[i][j]  = (f32x4){0.f, 0.f, 0.f, 0.f};
            av[i][j]  = (f32x4){0.f, 0.f, 0.f, 0.f};
            akk[i][j] = (f32x4){0.f, 0.f, 0.f, 0.f};
        }
    aqp[0] = (f32x4){0.f, 0.f, 0.f, 0.f};
    aqp[1] = (f32x4){0.f, 0.f, 0.f, 0.f};
    const short8 z8 = {0, 0, 0, 0, 0, 0, 0, 0};
    const short8* W8 = (const short8*)Wf;

#pragma unroll
    for (int kt = 0; kt < 8; ++kt) {
        const int ko = kt * 32 + qd * 8;
        short8 ay0 = *(const short8*)&Ys[ln * LDA + ko];
        short8 ay1 = *(const short8*)&Ys[(16 + ln) * LDA + ko];
        short8 ax0 = *(const short8*)&Xs[ln * LDA + ko];
        short8 ax1 = *(const short8*)&Xs[(16 + ln) * LDA + ko];
        short8 ext = *(const short8*)&Ys[32 * LDA + ko];   // broadcast read
        short8 ayp = (ln == 15) ? ext : z8;                // masked A-frag
#pragma unroll
        for (int jj = 0; jj < 2; ++jj) {
            const int jt = w * 2 + jj;
            short8 bq = W8[(((0 * 16 + jt) * 8 + kt) << 6) + lane];
            short8 bv = W8[(((1 * 16 + jt) * 8 + kt) << 6) + lane];
            short8 bk = W8[(((2 * 16 + jt) * 8 + kt) << 6) + lane];
            aq[0][jj]  = __builtin_amdgcn_mfma_f32_16x16x32_bf16(ay0, bq, aq[0][jj], 0, 0, 0);
            aq[1][jj]  = __builtin_amdgcn_mfma_f32_16x16x32_bf16(ay1, bq, aq[1][jj], 0, 0, 0);
            aqp[jj]    = __builtin_amdgcn_mfma_f32_16x16x32_bf16(ayp, bq, aqp[jj], 0, 0, 0);
            av[0][jj]  = __builtin_amdgcn_mfma_f32_16x16x32_bf16(ax0, bv, av[0][jj], 0, 0, 0);
            av[1][jj]  = __builtin_amdgcn_mfma_f32_16x16x32_bf16(ax1, bv, av[1][jj], 0, 0, 0);
            akk[0][jj] = __builtin_amdgcn_mfma_f32_16x16x32_bf16(ax0, bk, akk[0][jj], 0, 0, 0);
            akk[1][jj] = __builtin_amdgcn_mfma_f32_16x16x32_bf16(ax1, bk, akk[1][jj], 0, 0, 0);
        }
    }

    // ---- phi on q; boundary pprev (row 15 of masked tile = row mbase-1) ----
#pragma unroll
    for (int i = 0; i < 2; ++i)
#pragma unroll
        for (int jj = 0; jj < 2; ++jj)
#pragma unroll
            for (int r = 0; r < 4; ++r) aq[i][jj][r] = phi_f(aq[i][jj][r]);
    float pprev[2];
#pragma unroll
    for (int jj = 0; jj < 2; ++jj) {
        float p15 = __shfl(aqp[jj][3], 48 + ln);   // (qd=3,r=3) = row 15, col ln
        pprev[jj] = hasprev ? phi_f(p15) : 0.f;
    }

    // ---- c, cden per (row, head): dpq chain via shuffles ----
    float cc_[2][4], cd_[2][4];
#pragma unroll
    for (int i = 0; i < 2; ++i)
#pragma unroll
        for (int r = 0; r < 4; ++r) { cc_[i][r] = 0.f; cd_[i][r] = 0.f; }
#pragma unroll
    for (int jj = 0; jj < 2; ++jj) {
        float carry = pprev[jj];
#pragma unroll
        for (int i = 0; i < 2; ++i) {
            const float p0 = aq[i][jj][0], p1 = aq[i][jj][1], p2 = aq[i][jj][2], p3 = aq[i][jj][3];
            const float up3 = __shfl_up(p3, 16);
            const float prev0 = (qd == 0) ? carry : up3;
            const float d0 = p0 - prev0, d1 = p1 - p0, d2 = p2 - p1, d3 = p3 - p2;
            cc_[i][0] += d0 * av[i][jj][0]; cd_[i][0] += d0;
            cc_[i][1] += d1 * av[i][jj][1]; cd_[i][1] += d1;
            cc_[i][2] += d2 * av[i][jj][2]; cd_[i][2] += d2;
            cc_[i][3] += d3 * av[i][jj][3]; cd_[i][3] += d3;
            carry = __shfl(p3, ln + 48);
        }
    }
#pragma unroll
    for (int i = 0; i < 2; ++i)
#pragma unroll
        for (int r = 0; r < 4; ++r) {
            float x = cc_[i][r];
            x += __shfl_xor(x, 1); x += __shfl_xor(x, 2);
            x += __shfl_xor(x, 4); x += __shfl_xor(x, 8);
            float y = cd_[i][r];
            y += __shfl_xor(y, 1); y += __shfl_xor(y, 2);
            y += __shfl_xor(y, 4); y += __shfl_xor(y, 8);
            if (ln == 0) {
                scc[i * 16 + qd * 4 + r][w] = x;
                scd[i * 16 + qd * 4 + r][w] = y;
            }
        }
    __syncthreads();
    {
        const int idx = t & 255, row = idx & 31, h = idx >> 5;
        const size_t gi = (size_t)(n * 8 + h) * 8192 + lseg0 + row;
        if (t < 256) c_out[gi]  = scc[row][h];
        else         cd_out[gi] = scd[row][h];
    }

    // ---- phi on k; 32-row tile totals ----
#pragma unroll
    for (int i = 0; i < 2; ++i)
#pragma unroll
        for (int jj = 0; jj < 2; ++jj)
#pragma unroll
            for (int r = 0; r < 4; ++r) akk[i][jj][r] = phi_f(akk[i][jj][r]);
#pragma unroll
    for (int jj = 0; jj < 2; ++jj) {
        float tn = 0.f, td = 0.f;
#pragma unroll
        for (int i = 0; i < 2; ++i)
#pragma unroll
            for (int r = 0; r < 4; ++r) {
                const int row = i * 16 + qd * 4 + r;
                const float pv = akk[i][jj][r];
                tn += scc[row][w] * pv;
                td += scd[row][w] * pv;
            }
        tn += __shfl_xor(tn, 16); tn += __shfl_xor(tn, 32);
        td += __shfl_xor(td, 16); td += __shfl_xor(td, 32);
        if (qd == 0) {
            const int d = jj * 16 + ln;
            const size_t bi = ((size_t)(n * 8 + w) * 256 + tile) * 64;
            tot[bi + d]      = tn;
            tot[bi + 32 + d] = td;
        }
    }

    // ---- pk -> global bf16 via LDS transpose ----
#pragma unroll
    for (int i = 0; i < 2; ++i)
#pragma unroll
        for (int jj = 0; jj < 2; ++jj)
#pragma unroll
            for (int r = 0; r < 4; ++r)
                spk[(i * 16 + qd * 4 + r) * 264 + w * 32 + jj * 16 + ln] = f2bf(akk[i][jj][r]);
    __syncthreads();
#pragma unroll
    for (int it = 0; it < 2; ++it) {
        const int idx = t + 512 * it;     // 1024 chunks (32 rows x 32 col-groups)
        const int row = idx >> 5, cg = idx & 31;
        short8 vals = *(const short8*)&spk[row * 264 + cg * 8];
        const int head = cg >> 2, d8 = (cg & 3) * 8;
        *(short8*)(pk_out + ((size_t)(n * 8 + head) * 8192 + lseg0 + row) * 32 + d8) = vals;
    }
}

// ---------------- K3: prefix + scan + divide + store ----------------------
// grid 1024 = 16 segs x 64 blocks (128 rows). Lanes 0..127 walk 32 rows each
// carrying BOTH running num and den.
__global__ __launch_bounds__(256) void k_scan(
        const unsigned short* __restrict__ pk, const float* __restrict__ c,
        const float* __restrict__ cd, const float* __restrict__ tot,
        float* __restrict__ out)
{
    __shared__ __align__(16) unsigned short spk[128 * 32];  // 8 KB
    __shared__ float sc[128], sd[128];
    __shared__ float wsum[4][64], stile[4][64];

    const int bx = blockIdx.x, seg = bx >> 6, blk = bx & 63;
    const int n = seg >> 3, h = seg & 7;
    const int t = threadIdx.x, l0 = blk * 128;
    const int wv = t >> 6, lane = t & 63;
    const int T = blk * 4;                // preceding 32-row tiles

    // deep-ILP prefix over preceding tile totals (8 loads in flight)
    const float* tb = tot + (size_t)seg * 256 * 64 + lane;
    float p0 = 0.f, p1 = 0.f, p2 = 0.f, p3 = 0.f,
          p4 = 0.f, p5 = 0.f, p6 = 0.f, p7 = 0.f;
    int i = wv;
    for (; i + 28 < T; i += 32) {
        p0 += tb[(i)      * 64]; p1 += tb[(i + 4)  * 64];
        p2 += tb[(i + 8)  * 64]; p3 += tb[(i + 12) * 64];
        p4 += tb[(i + 16) * 64]; p5 += tb[(i + 20) * 64];
        p6 += tb[(i + 24) * 64]; p7 += tb[(i + 28) * 64];
    }
    for (; i < T; i += 4) p0 += tb[i * 64];
    wsum[wv][lane]  = ((p0 + p1) + (p2 + p3)) + ((p4 + p5) + (p6 + p7));
    stile[wv][lane] = tb[(T + wv) * 64];  // own-block tile totals

#pragma unroll
    for (int it = 0; it < 2; ++it) {
        const int idx = t + 256 * it;     // 512 short8 chunks, identical layout
        *(short8*)&spk[idx * 8] = *(const short8*)(pk + ((size_t)seg * 8192 + l0) * 32 + idx * 8);
    }
    if (t < 128) sc[t] = c[(size_t)seg * 8192 + l0 + t];
    else         sd[t - 128] = cd[(size_t)seg * 8192 + l0 + (t - 128)];
    __syncthreads();

    if (t < 128) {
        const int g = t >> 5, d = t & 31; // group g: rows g*32..+31
        float rn  = (wsum[0][d] + wsum[1][d]) + (wsum[2][d] + wsum[3][d]);
        float rd_ = (wsum[0][32 + d] + wsum[1][32 + d]) + (wsum[2][32 + d] + wsum[3][32 + d]);
#pragma unroll
        for (int i2 = 0; i2 < 3; ++i2)
            if (i2 < g) { rn += stile[i2][d]; rd_ += stile[i2][32 + d]; }
        float* ob = out + ((size_t)n * 8192 + l0 + g * 32) * 256 + h * 32 + d;
#pragma unroll
        for (int p = 0; p < 32; ++p) {
            const int m = g * 32 + p;
            const float pkv = bf2f(spk[m * 32 + d]);
            rn  += sc[m] * pkv;
            rd_ += sd[m] * pkv;
            ob[(size_t)p * 256] = rn / rd_;   // div off the carried chain
        }
    }
}

extern "C" void kernel_launch(void* const* d_in, const int* in_sizes, int n_in,
                              void* d_out, int out_size, void* d_ws, size_t ws_size,
                              hipStream_t stream)
{
    const float* Y  = (const float*)d_in[0];
    const float* X  = (const float*)d_in[1];
    const float* Wq = (const float*)d_in[2];
    const float* Wk = (const float*)d_in[3];
    const float* Wv = (const float*)d_in[4];
    float* out = (float*)d_out;

    float* ws = (float*)d_ws;
    unsigned short* Wf = (unsigned short*)ws;                 // 196608 bf16
    unsigned short* pk = (unsigned short*)(ws + 98304);       // 4194304 bf16
    float* c   = ws + 98304 + 2097152;
    float* cd  = c  + 131072;
    float* tot = cd + 131072;    // 16*256*64

    hipLaunchKernelGGL(k_prepw, dim3(96),   dim3(256), 0, stream, Wq, Wk, Wv, Wf);
    hipLaunchKernelGGL(k_gemm,  dim3(512),  dim3(512), 0, stream,
                       Y, X, Wf, pk, c, cd, tot);
    hipLaunchKernelGGL(k_scan,  dim3(1024), dim3(256), 0, stream, pk, c, cd, tot, out);
}